// Round 3
// baseline (2105.647 us; speedup 1.0000x reference)
//
#include <hip/hip_runtime.h>
#include <hip/hip_cooperative_groups.h>
#include <math.h>

namespace cg = cooperative_groups;

#define Bn  16
#define Nn  127
#define NP  256
#define NSQ (NP*NP)       // 65536
#define RSZ (Nn*Nn)       // 16129

// ---------------- static device workspace ----------------
__device__ float2 g_CA[Bn*4*NSQ];   // 33.5 MB
__device__ float2 g_CB[Bn*4*NSQ];   // 33.5 MB
__device__ float  g_x [Bn*RSZ];
__device__ float  g_xB[Bn*RSZ];
__device__ float  g_r [Bn*RSZ];
__device__ float2 g_W1 [Bn*4*9];
__device__ float2 g_W1T[Bn*4*9];
__device__ float2 g_W2 [Bn*16*9];
__device__ float2 g_W2T[Bn*16*9];
__device__ float2 g_W3 [Bn*4*9];
__device__ float2 g_W3T[Bn*4*9];
__device__ float2 g_twid[128];      // e^{+2pi i m/256}
__device__ float  g_acc[2];
__device__ int    g_K;

// ---------------- init: K, zero xB/acc, twiddles, canonical weights ----------------
__global__ void init_kernel(const float* __restrict__ w1r, const float* __restrict__ w1i,
                            const float* __restrict__ w2r, const float* __restrict__ w2i,
                            const float* __restrict__ w3r, const float* __restrict__ w3i,
                            const int* __restrict__ epoch)
{
    int tid = threadIdx.x;
    if (tid == 0) {
        int e = epoch[0];
        int K = (e - 1) / 40 + 1;
        if (K > 10) K = 10;
        if (K < 1)  K = 1;
        g_K = K;
    }
    if (tid < 2) g_acc[tid] = 0.f;
    for (int i = tid; i < Bn*RSZ; i += 256) g_xB[i] = 0.f;
    if (tid < 128) {
        float sn, cs;
        sincosf(6.283185307179586f * (float)tid / 256.f, &sn, &cs);
        g_twid[tid] = make_float2(cs, sn);
    }

    for (int o = tid; o < Bn*36; o += 256) {
        int k = o % 9;
        int a = k / 3, bb = k % 3;
        int c = (o / 9) % 4;
        int b = o / 36;
        int src = b*36 + c*9 + bb*3 + a;
        g_W1 [o] = make_float2(w1r[o],  w1i[o]);
        g_W1T[o] = make_float2(w1r[src], -w1i[src]);
        g_W3 [o] = make_float2(w3r[o],  w3i[o]);
        g_W3T[o] = make_float2(w3r[src], -w3i[src]);
    }
    for (int o = tid; o < Bn*144; o += 256) {
        int k = o % 9;
        int a = k / 3, bb = k % 3;
        int ci = (o / 9) % 4;
        int co = (o / 36) % 4;
        int b  = o / 144;
        int src = b*144 + ci*36 + co*9 + bb*3 + a;
        g_W2 [o] = make_float2(w2r[o],  w2i[o]);
        g_W2T[o] = make_float2(w2r[src], -w2i[src]);
    }
}

// ---------------- odd-symmetric expand value ----------------
__device__ __forceinline__ float expand_val(const float* __restrict__ r, int b, int m, int n)
{
    if (m == 0 || m == 128 || n == 0 || n == 128) return 0.f;
    float s = 1.f; int mr, nc;
    if (m < 128) { mr = m - 1; } else { mr = 255 - m; s = -s; }
    if (n < 128) { nc = n - 1; } else { nc = 255 - n; s = -s; }
    return s * r[b*RSZ + mr*Nn + nc];
}

// ---------------- phase: Jacobi (halo-tiled, 20 steps + residual) ----------------
__device__ __forceinline__ void jacobi_phase(float* smem, const float* __restrict__ f,
                                             const float* __restrict__ kA, int bid, int tid)
{
    float* buf0 = smem;
    float* buf1 = smem + 6080;
    const int b  = bid >> 4;
    const int ti = (bid >> 2) & 3, tj = bid & 3;
    const int gr0 = ti*32 - 21, gc0 = tj*32 - 21;

    float ka[9];
#pragma unroll
    for (int k = 0; k < 9; ++k) ka[k] = kA[b*9 + k];
    const float tau = 0.5f / ka[4];

    for (int i = tid; i < 76*80; i += 512) { buf0[i] = 0.f; buf1[i] = 0.f; }

    int   off[6]; float fv0[6], fv1[6], mm0[6], mm1[6], x00[6], x01[6];
#pragma unroll
    for (int q = 0; q < 6; ++q) {
        int idx = tid + q*512;
        bool valid = idx < 74*37;
        int rr = idx / 37, pp = idx - rr*37;
        int gr = gr0 + rr;
        int gc = gc0 + pp*2;
        bool rowok = valid && gr >= 0 && gr < Nn;
        bool c0 = rowok && gc >= 0 && gc < Nn;
        bool c1 = rowok && (gc+1) >= 0 && (gc+1) < Nn;
        off[q] = valid ? ((1+rr)*80 + 3 + 2*pp) : -1;
        mm0[q] = c0 ? 1.f : 0.f;
        mm1[q] = c1 ? 1.f : 0.f;
        fv0[q] = c0 ? f[b*RSZ + gr*Nn + gc]     : 0.f;
        fv1[q] = c1 ? f[b*RSZ + gr*Nn + gc + 1] : 0.f;
        x00[q] = c0 ? g_xB[b*RSZ + gr*Nn + gc]     : 0.f;
        x01[q] = c1 ? g_xB[b*RSZ + gr*Nn + gc + 1] : 0.f;
    }
    __syncthreads();
#pragma unroll
    for (int q = 0; q < 6; ++q) {
        if (off[q] < 0) continue;
        buf0[off[q]]     = x00[q];
        buf0[off[q] + 1] = x01[q];
    }

    for (int s = 0; s < 20; ++s) {
        __syncthreads();
        const float* ob = (s & 1) ? buf1 : buf0;
        float*       nb = (s & 1) ? buf0 : buf1;
#pragma unroll
        for (int q = 0; q < 6; ++q) {
            int o = off[q];
            if (o < 0) continue;
            float2 a0 = *(const float2*)(ob + o - 81);
            float2 b0 = *(const float2*)(ob + o - 79);
            float2 a1 = *(const float2*)(ob + o - 1);
            float2 b1 = *(const float2*)(ob + o + 1);
            float2 a2 = *(const float2*)(ob + o + 79);
            float2 b2 = *(const float2*)(ob + o + 81);
            float c0 = ka[0]*a0.x + ka[1]*a0.y + ka[2]*b0.x
                     + ka[3]*a1.x + ka[4]*a1.y + ka[5]*b1.x
                     + ka[6]*a2.x + ka[7]*a2.y + ka[8]*b2.x;
            float c1 = ka[0]*a0.y + ka[1]*b0.x + ka[2]*b0.y
                     + ka[3]*a1.y + ka[4]*b1.x + ka[5]*b1.y
                     + ka[6]*a2.y + ka[7]*b2.x + ka[8]*b2.y;
            nb[o]     = (a1.y + tau*(fv0[q] - c0)) * mm0[q];
            nb[o + 1] = (b1.x + tau*(fv1[q] - c1)) * mm1[q];
        }
    }
    __syncthreads();
    for (int idx = tid; idx < 32*32; idx += 512) {
        int a = idx >> 5, c = idx & 31;
        int gr = ti*32 + a, gc = tj*32 + c;
        if (gr >= Nn || gc >= Nn) continue;
        int o = (22 + a)*80 + 24 + c;
        float conv = ka[0]*buf0[o-81] + ka[1]*buf0[o-80] + ka[2]*buf0[o-79]
                   + ka[3]*buf0[o-1]  + ka[4]*buf0[o]    + ka[5]*buf0[o+1]
                   + ka[6]*buf0[o+79] + ka[7]*buf0[o+80] + ka[8]*buf0[o+81];
        int g = b*RSZ + gr*Nn + gc;
        g_x[g] = buf0[o];
        g_r[g] = f[g] - conv;
    }
}

// ---------------- phase: 256-pt Stockham FFT, 16 lines/block (4 slots x 4 loops) ----------------
template<int SIGN, bool COLS, bool EXPAND>
__device__ __forceinline__ void fft_phase(float* smem, const float2* s_tw,
                                          const float2* __restrict__ in, float2* __restrict__ out,
                                          float scale, int bid, int tid)
{
    float2 (*bufA)[256] = (float2 (*)[256])smem;
    float2 (*bufB)[256] = bufA + 4;
    const int slot = tid >> 7;
    const int t    = tid & 127;

    for (int lp = 0; lp < 4; ++lp) {
        __syncthreads();
        const int line = bid*16 + lp*4 + slot;
        const int b    = line >> 8;
        const int pos  = line & 255;
        const int base = (b*4) << 16;

#pragma unroll
        for (int h = 0; h < 2; ++h) {
            int e = t + (h << 7);
            float2 v;
            if (EXPAND)    v = make_float2(expand_val(g_r, b, pos, e), 0.f);
            else if (COLS) v = in[base + e*NP + pos];
            else           v = in[base + pos*NP + e];
            bufA[slot][e] = v;
        }
        __syncthreads();

        float2* X = bufA[slot];
        float2* Y = bufB[slot];
#pragma unroll
        for (int k = 0; k < 8; ++k) {
            int s = 1 << k;
            int p = t >> k;
            int q = t & (s - 1);
            float2 a = X[q + s*p];
            float2 c = X[q + s*(p + (128 >> k))];
            float2 w = s_tw[p << k];
            float cs = w.x;
            float sn = (SIGN > 0) ? w.y : -w.y;
            float2 sum = make_float2(a.x + c.x, a.y + c.y);
            float2 d   = make_float2(a.x - c.x, a.y - c.y);
            float2 dw  = make_float2(d.x*cs - d.y*sn, d.x*sn + d.y*cs);
            Y[q + s*(2*p)]     = sum;
            Y[q + s*(2*p + 1)] = dw;
            __syncthreads();
            float2* tmp = X; X = Y; Y = tmp;
        }

#pragma unroll
        for (int h = 0; h < 2; ++h) {
            int e = t + (h << 7);
            float2 v = X[e];
            v.x *= scale; v.y *= scale;
            if (COLS) out[base + e*NP + pos] = v;
            else      out[base + pos*NP + e] = v;
        }
    }
}

// ---------------- phase: complex grouped 3x3 conv, sliding window ----------------
template<int CIN, int COUT, int RPU, int WID, bool SL, bool SS, bool THETA>
__device__ __forceinline__ void conv_phase(const float2* __restrict__ in, float2* __restrict__ out,
                                           const float* __restrict__ thr, const float* __restrict__ thi,
                                           int bid, int tid)
{
    const float2* W =
        (WID == 0) ? g_W1 : (WID == 1) ? g_W2 : (WID == 2) ? g_W3 :
        (WID == 3) ? g_W3T : (WID == 4) ? g_W2T : g_W1T;
    const int j   = tid & 255;
    const int grp = bid*2 + (tid >> 8);
    const int NRG = 256 / RPU;
    const int NU  = Bn * COUT * NRG;

    for (int u = grp; u < NU; u += 512) {
        const int rg = u & (NRG - 1);
        const int co = (u / NRG) & (COUT - 1);
        const int b  = u / (NRG * COUT);

        float2 w[CIN][9];
        const float2* Wp = W + ((b*COUT + co)*CIN)*9;
#pragma unroll
        for (int ci = 0; ci < CIN; ++ci)
#pragma unroll
            for (int k = 0; k < 9; ++k) w[ci][k] = Wp[ci*9 + k];

        auto ld = [&](int ci, int si, int sj) -> float2 {
            if (si < 0 || si >= NP || sj < 0 || sj >= NP) return make_float2(0.f, 0.f);
            int r = SL ? ((si + 128) & 255) : si;
            int c = SL ? ((sj + 128) & 255) : sj;
            return in[((b*4 + ci) << 16) + r*NP + c];
        };

        float2 win[CIN][3][3];
        const int i0 = rg * RPU;
#pragma unroll
        for (int ci = 0; ci < CIN; ++ci)
#pragma unroll
            for (int c = 0; c < 3; ++c) {
                win[ci][0][c] = ld(ci, i0 - 1, j - 1 + c);
                win[ci][1][c] = ld(ci, i0,     j - 1 + c);
            }

        for (int i = i0; i < i0 + RPU; ++i) {
#pragma unroll
            for (int ci = 0; ci < CIN; ++ci)
#pragma unroll
                for (int c = 0; c < 3; ++c)
                    win[ci][2][c] = ld(ci, i + 1, j - 1 + c);

            float2 acc = make_float2(0.f, 0.f);
#pragma unroll
            for (int ci = 0; ci < CIN; ++ci)
#pragma unroll
                for (int r = 0; r < 3; ++r)
#pragma unroll
                    for (int c = 0; c < 3; ++c) {
                        float2 v  = win[ci][r][c];
                        float2 ww = w[ci][r*3 + c];
                        acc.x += v.x*ww.x - v.y*ww.y;
                        acc.y += v.x*ww.y + v.y*ww.x;
                    }
            if (THETA) {
                float tr  = thr[b*NSQ + i*NP + j];
                float ti2 = thi[b*NSQ + i*NP + j];
                acc = make_float2(acc.x*tr - acc.y*ti2, acc.x*ti2 + acc.y*tr);
            }
            int oi = SS ? ((i + 128) & 255) : i;
            int oj = SS ? ((j + 128) & 255) : j;
            out[((b*4 + co) << 16) + oi*NP + oj] = acc;

#pragma unroll
            for (int ci = 0; ci < CIN; ++ci)
#pragma unroll
                for (int c = 0; c < 3; ++c) {
                    win[ci][0][c] = win[ci][1][c];
                    win[ci][1][c] = win[ci][2][c];
                }
        }
    }
}

// ---------------- phase: x_new = x + e ; r = f - A(x+e) ----------------
__device__ __forceinline__ void xupd_phase(const float* __restrict__ f,
                                           const float* __restrict__ kA, int bid, int tid)
{
    for (int idx = bid*512 + tid; idx < Bn*RSZ; idx += 131072) {
        int b = idx / RSZ, rem = idx - b*RSZ;
        int i = rem / Nn, j = rem - i*Nn;
        const float2* e = g_CB + ((b*4) << 16);
        float acc = 0.f;
#pragma unroll
        for (int a = 0; a < 3; ++a) {
            int si = i + a - 1;
            if (si < 0 || si >= Nn) continue;
#pragma unroll
            for (int b2 = 0; b2 < 3; ++b2) {
                int sj = j + b2 - 1;
                if (sj < 0 || sj >= Nn) continue;
                float xv = g_x[b*RSZ + si*Nn + sj] + e[si*NP + sj].x;
                acc += xv * kA[b*9 + a*3 + b2];
            }
        }
        g_xB[idx] = g_x[idx] + e[i*NP + j].x;
        g_r[idx]  = f[idx] - acc;
    }
}

// ---------------- phase: norm partial reduce ----------------
__device__ __forceinline__ void norm_phase(float* smem, const float* __restrict__ f, int bid, int tid)
{
    float ar = 0.f, af = 0.f;
    for (int i = bid*512 + tid; i < Bn*RSZ; i += 131072) {
        float rv = g_r[i]; ar += rv*rv;
        float fv = f[i];   af += fv*fv;
    }
    float* sr = smem;
    float* sf = smem + 512;
    sr[tid] = ar; sf[tid] = af;
    __syncthreads();
    for (int s = 256; s > 0; s >>= 1) {
        if (tid < s) { sr[tid] += sr[tid+s]; sf[tid] += sf[tid+s]; }
        __syncthreads();
    }
    if (tid == 0) {
        atomicAdd(&g_acc[0], sr[0]);
        atomicAdd(&g_acc[1], sf[0]);
    }
}

// ---------------- the cooperative mega-kernel ----------------
__global__ __launch_bounds__(512) void mega_kernel(const float* __restrict__ f,
                                                   const float* __restrict__ kA,
                                                   const float* __restrict__ thr,
                                                   const float* __restrict__ thi,
                                                   float* __restrict__ out)
{
    cg::grid_group grid = cg::this_grid();
    __shared__ __align__(16) float smem[12160];   // 48640 B (jacobi is the max user)
    __shared__ float2 s_tw[128];

    const int tid = threadIdx.x;
    const int bid = blockIdx.x;

    for (int m = tid; m < 128; m += 512) s_tw[m] = g_twid[m];
    const int K = g_K;
    __syncthreads();

    const float inv256 = 1.f / 256.f;

    for (int it = 0; it < K; ++it) {
        jacobi_phase(smem, f, kA, bid, tid);
        grid.sync();
        fft_phase<1, false, true >(smem, s_tw, g_CB, g_CA, inv256, bid, tid);  // expand rows -> CA
        grid.sync();
        fft_phase<1, true,  false>(smem, s_tw, g_CA, g_CB, inv256, bid, tid);  // cols CA -> CB
        grid.sync();
        conv_phase<1,4,16,0,true, false,false>(g_CB, g_CA, thr, thi, bid, tid); // conv1 (shift-load)
        grid.sync();
        conv_phase<4,4,16,1,false,false,false>(g_CA, g_CB, thr, thi, bid, tid); // conv2
        grid.sync();
        conv_phase<4,1, 8,2,false,false,true >(g_CB, g_CA, thr, thi, bid, tid); // conv3 * theta
        grid.sync();
        conv_phase<1,4,16,3,false,false,false>(g_CA, g_CB, thr, thi, bid, tid); // conv3T
        grid.sync();
        conv_phase<4,4,16,4,false,false,false>(g_CB, g_CA, thr, thi, bid, tid); // conv2T
        grid.sync();
        conv_phase<4,1, 8,5,false,true, false>(g_CA, g_CB, thr, thi, bid, tid); // conv1T (shift-store)
        grid.sync();
        fft_phase<-1, false, false>(smem, s_tw, g_CB, g_CA, 1.f, bid, tid);     // fwd rows CB -> CA
        grid.sync();
        fft_phase<-1, true,  false>(smem, s_tw, g_CA, g_CB, 1.f, bid, tid);     // fwd cols CA -> CB
        grid.sync();
        xupd_phase(f, kA, bid, tid);
        grid.sync();
    }

    norm_phase(smem, f, bid, tid);
    grid.sync();
    if (bid == 0 && tid == 0) out[0] = sqrtf(g_acc[0] / g_acc[1]);
}

// ---------------- driver ----------------
extern "C" void kernel_launch(void* const* d_in, const int* in_sizes, int n_in,
                              void* d_out, int out_size, void* d_ws, size_t ws_size,
                              hipStream_t stream)
{
    const float* f   = (const float*)d_in[0];
    const float* kA  = (const float*)d_in[1];
    const float* w1r = (const float*)d_in[2];
    const float* w1i = (const float*)d_in[3];
    const float* w2r = (const float*)d_in[4];
    const float* w2i = (const float*)d_in[5];
    const float* w3r = (const float*)d_in[6];
    const float* w3i = (const float*)d_in[7];
    const float* thr = (const float*)d_in[8];
    const float* thi = (const float*)d_in[9];
    const int* epoch = (const int*)d_in[10];
    float* out = (float*)d_out;

    init_kernel<<<1, 256, 0, stream>>>(w1r, w1i, w2r, w2i, w3r, w3i, epoch);

    void* args[5];
    args[0] = (void*)&f;
    args[1] = (void*)&kA;
    args[2] = (void*)&thr;
    args[3] = (void*)&thi;
    args[4] = (void*)&out;
    hipLaunchCooperativeKernel(reinterpret_cast<void*>(mega_kernel),
                               dim3(256), dim3(512), args, 0, stream);
}

// Round 4
// 887.507 us; speedup vs baseline: 2.3725x; 2.3725x over previous
//
#include <hip/hip_runtime.h>
#include <math.h>

#define Bn  16
#define Nn  127
#define NP  256
#define NSQ (NP*NP)       // 65536
#define RSZ (Nn*Nn)       // 16129

// ---------------- static device workspace ----------------
__device__ float2 g_CA[Bn*4*NSQ];   // 33.5 MB
__device__ float2 g_CB[Bn*4*NSQ];   // 33.5 MB
__device__ float  g_x [Bn*RSZ];
__device__ float  g_xB[Bn*RSZ];
__device__ float  g_r [Bn*RSZ];
__device__ float2 g_W1 [Bn*4*9];
__device__ float2 g_W1T[Bn*4*9];
__device__ float2 g_W2 [Bn*16*9];
__device__ float2 g_W2T[Bn*16*9];
__device__ float2 g_W3 [Bn*4*9];
__device__ float2 g_W3T[Bn*4*9];
__device__ float2 g_twid[128];      // e^{+2pi i m/256}
__device__ float  g_acc[2];
__device__ int    g_K;

// ---------------- init ----------------
__global__ void init_kernel(const float* __restrict__ w1r, const float* __restrict__ w1i,
                            const float* __restrict__ w2r, const float* __restrict__ w2i,
                            const float* __restrict__ w3r, const float* __restrict__ w3i,
                            const int* __restrict__ epoch)
{
    int tid = threadIdx.x;
    if (tid == 0) {
        int e = epoch[0];
        int K = (e - 1) / 40 + 1;
        if (K > 10) K = 10;
        if (K < 1)  K = 1;
        g_K = K;
    }
    if (tid < 2) g_acc[tid] = 0.f;
    for (int i = tid; i < Bn*RSZ; i += 256) g_xB[i] = 0.f;
    if (tid < 128) {
        float sn, cs;
        sincosf(6.283185307179586f * (float)tid / 256.f, &sn, &cs);
        g_twid[tid] = make_float2(cs, sn);
    }

    for (int o = tid; o < Bn*36; o += 256) {
        int k = o % 9;
        int a = k / 3, bb = k % 3;
        int c = (o / 9) % 4;
        int b = o / 36;
        int src = b*36 + c*9 + bb*3 + a;
        g_W1 [o] = make_float2(w1r[o],  w1i[o]);
        g_W1T[o] = make_float2(w1r[src], -w1i[src]);
        g_W3 [o] = make_float2(w3r[o],  w3i[o]);
        g_W3T[o] = make_float2(w3r[src], -w3i[src]);
    }
    for (int o = tid; o < Bn*144; o += 256) {
        int k = o % 9;
        int a = k / 3, bb = k % 3;
        int ci = (o / 9) % 4;
        int co = (o / 36) % 4;
        int b  = o / 144;
        int src = b*144 + ci*36 + co*9 + bb*3 + a;
        g_W2 [o] = make_float2(w2r[o],  w2i[o]);
        g_W2T[o] = make_float2(w2r[src], -w2i[src]);
    }
}

// ---------------- Jacobi: halo-tiled, 20 steps + residual ----------------
__global__ __launch_bounds__(512) void jacobi_kernel(const float* __restrict__ f,
                                                     const float* __restrict__ kA, int it)
{
    if (it >= g_K) return;
    __shared__ float buf0[76*80];
    __shared__ float buf1[76*80];
    const int tid = threadIdx.x;
    const int b  = blockIdx.z;
    const int ti = blockIdx.y, tj = blockIdx.x;
    const int gr0 = ti*32 - 21, gc0 = tj*32 - 21;

    float ka[9];
#pragma unroll
    for (int k = 0; k < 9; ++k) ka[k] = kA[b*9 + k];
    const float tau = 0.5f / ka[4];

    for (int i = tid; i < 76*80; i += 512) { buf0[i] = 0.f; buf1[i] = 0.f; }

    int   off[6]; float fv0[6], fv1[6], mm0[6], mm1[6], x00[6], x01[6];
#pragma unroll
    for (int q = 0; q < 6; ++q) {
        int idx = tid + q*512;
        bool valid = idx < 74*37;
        int rr = idx / 37, pp = idx - rr*37;
        int gr = gr0 + rr;
        int gc = gc0 + pp*2;
        bool rowok = valid && gr >= 0 && gr < Nn;
        bool c0 = rowok && gc >= 0 && gc < Nn;
        bool c1 = rowok && (gc+1) >= 0 && (gc+1) < Nn;
        off[q] = valid ? ((1+rr)*80 + 3 + 2*pp) : -1;
        mm0[q] = c0 ? 1.f : 0.f;
        mm1[q] = c1 ? 1.f : 0.f;
        fv0[q] = c0 ? f[b*RSZ + gr*Nn + gc]     : 0.f;
        fv1[q] = c1 ? f[b*RSZ + gr*Nn + gc + 1] : 0.f;
        x00[q] = c0 ? g_xB[b*RSZ + gr*Nn + gc]     : 0.f;
        x01[q] = c1 ? g_xB[b*RSZ + gr*Nn + gc + 1] : 0.f;
    }
    __syncthreads();
#pragma unroll
    for (int q = 0; q < 6; ++q) {
        if (off[q] < 0) continue;
        buf0[off[q]]     = x00[q];
        buf0[off[q] + 1] = x01[q];
    }

    for (int s = 0; s < 20; ++s) {
        __syncthreads();
        const float* ob = (s & 1) ? buf1 : buf0;
        float*       nb = (s & 1) ? buf0 : buf1;
#pragma unroll
        for (int q = 0; q < 6; ++q) {
            int o = off[q];
            if (o < 0) continue;
            float2 a0 = *(const float2*)(ob + o - 81);
            float2 b0 = *(const float2*)(ob + o - 79);
            float2 a1 = *(const float2*)(ob + o - 1);
            float2 b1 = *(const float2*)(ob + o + 1);
            float2 a2 = *(const float2*)(ob + o + 79);
            float2 b2 = *(const float2*)(ob + o + 81);
            float c0 = ka[0]*a0.x + ka[1]*a0.y + ka[2]*b0.x
                     + ka[3]*a1.x + ka[4]*a1.y + ka[5]*b1.x
                     + ka[6]*a2.x + ka[7]*a2.y + ka[8]*b2.x;
            float c1 = ka[0]*a0.y + ka[1]*b0.x + ka[2]*b0.y
                     + ka[3]*a1.y + ka[4]*b1.x + ka[5]*b1.y
                     + ka[6]*a2.y + ka[7]*b2.x + ka[8]*b2.y;
            nb[o]     = (a1.y + tau*(fv0[q] - c0)) * mm0[q];
            nb[o + 1] = (b1.x + tau*(fv1[q] - c1)) * mm1[q];
        }
    }
    __syncthreads();
    for (int idx = tid; idx < 32*32; idx += 512) {
        int a = idx >> 5, c = idx & 31;
        int gr = ti*32 + a, gc = tj*32 + c;
        if (gr >= Nn || gc >= Nn) continue;
        int o = (22 + a)*80 + 24 + c;
        float conv = ka[0]*buf0[o-81] + ka[1]*buf0[o-80] + ka[2]*buf0[o-79]
                   + ka[3]*buf0[o-1]  + ka[4]*buf0[o]    + ka[5]*buf0[o+1]
                   + ka[6]*buf0[o+79] + ka[7]*buf0[o+80] + ka[8]*buf0[o+81];
        int g = b*RSZ + gr*Nn + gc;
        g_x[g] = buf0[o];
        g_r[g] = f[g] - conv;
    }
}

// ---------------- odd-symmetric expand value ----------------
__device__ __forceinline__ float expand_val(const float* __restrict__ r, int b, int m, int n)
{
    if (m == 0 || m == 128 || n == 0 || n == 128) return 0.f;
    float s = 1.f; int mr, nc;
    if (m < 128) { mr = m - 1; } else { mr = 255 - m; s = -s; }
    if (n < 128) { nc = n - 1; } else { nc = 255 - n; s = -s; }
    return s * r[b*RSZ + mr*Nn + nc];
}

// ---------------- 256-pt Stockham FFT, 8 lines per block ----------------
// sel==0: in=g_CA out=g_CB ; sel==1: in=g_CB out=g_CA (channel 0 only)
template<int SIGN, bool COLS, bool EXPAND>
__global__ __launch_bounds__(256) void fft_kernel(int sel, float scale, int it)
{
    if (it >= g_K) return;
    __shared__ float2 bufA[2][256];
    __shared__ float2 bufB[2][256];
    __shared__ float2 tw[128];
    const float2* __restrict__ in = sel ? g_CB : g_CA;
    float2* __restrict__ out      = sel ? g_CA : g_CB;

    for (int m = threadIdx.x; m < 128; m += 256) tw[m] = g_twid[m];

    int lid = threadIdx.x >> 7;
    int t   = threadIdx.x & 127;

    for (int lp = 0; lp < 4; ++lp) {
        __syncthreads();
        int line = blockIdx.x*8 + lp*2 + lid;
        int b    = line >> 8;
        int pos  = line & 255;
        int base = (b*4) << 16;

#pragma unroll
        for (int h = 0; h < 2; ++h) {
            int e = t + (h << 7);
            float2 v;
            if (EXPAND)    v = make_float2(expand_val(g_r, b, pos, e), 0.f);
            else if (COLS) v = in[base + e*NP + pos];
            else           v = in[base + pos*NP + e];
            bufA[lid][e] = v;
        }
        __syncthreads();

        float2* X = bufA[lid];
        float2* Y = bufB[lid];
#pragma unroll
        for (int k = 0; k < 8; ++k) {
            int s = 1 << k;
            int p = t >> k;
            int q = t & (s - 1);
            float2 a = X[q + s*p];
            float2 c = X[q + s*(p + (128 >> k))];
            float2 w = tw[p << k];
            float cs = w.x;
            float sn = (SIGN > 0) ? w.y : -w.y;
            float2 sum = make_float2(a.x + c.x, a.y + c.y);
            float2 d   = make_float2(a.x - c.x, a.y - c.y);
            float2 dw  = make_float2(d.x*cs - d.y*sn, d.x*sn + d.y*cs);
            Y[q + s*(2*p)]     = sum;
            Y[q + s*(2*p + 1)] = dw;
            __syncthreads();
            float2* tmp = X; X = Y; Y = tmp;
        }

#pragma unroll
        for (int h = 0; h < 2; ++h) {
            int e = t + (h << 7);
            float2 v = X[e];
            v.x *= scale; v.y *= scale;
            if (COLS) out[base + e*NP + pos] = v;
            else      out[base + pos*NP + e] = v;
        }
    }
}

// ---------------- fused conv stack: one stage of the chain ----------------
// src: CIN channels of RIN x RIN in LDS; dst: COUT channels of (RIN-2)^2 in LDS
// (or global ch0 with ifftshift store when STORE_GLOBAL). Producer-side zeroing
// implements SAME padding in shifted coords. sw layout: [co][ci][9].
template<int CIN, int COUT, int RIN, bool THETA, bool STORE_GLOBAL>
__device__ __forceinline__ void stage_conv(const float2* __restrict__ src, float2* __restrict__ dst,
                                           const float2* __restrict__ sw, int oi, int oj, int b,
                                           const float* __restrict__ thr, const float* __restrict__ thi,
                                           int tid, float2* __restrict__ gout)
{
    constexpr int ROUT = RIN - 2;
    constexpr int TOT  = ROUT * ROUT;
    constexpr int NS   = (TOT + 255) / 256;

    float2 acc[NS][COUT];
#pragma unroll
    for (int s = 0; s < NS; ++s)
#pragma unroll
        for (int co = 0; co < COUT; ++co) acc[s][co] = make_float2(0.f, 0.f);

#pragma unroll
    for (int ci = 0; ci < CIN; ++ci) {
        float2 wr[COUT*9];
#pragma unroll
        for (int k = 0; k < COUT*9; ++k) {
            int co = k / 9, t9 = k - co*9;
            wr[k] = sw[(co*CIN + ci)*9 + t9];
        }
        const float2* sp0 = src + ci*RIN*RIN;
#pragma unroll
        for (int s = 0; s < NS; ++s) {
            int p = tid + s*256;
            if (p < TOT) {
                int r = p / ROUT, c = p - r*ROUT;
                const float2* sp = sp0 + r*RIN + c;
                float2 dd[9];
                dd[0] = sp[0];       dd[1] = sp[1];       dd[2] = sp[2];
                dd[3] = sp[RIN];     dd[4] = sp[RIN+1];   dd[5] = sp[RIN+2];
                dd[6] = sp[2*RIN];   dd[7] = sp[2*RIN+1]; dd[8] = sp[2*RIN+2];
#pragma unroll
                for (int co = 0; co < COUT; ++co)
#pragma unroll
                    for (int t9 = 0; t9 < 9; ++t9) {
                        float2 v = dd[t9], w = wr[co*9 + t9];
                        acc[s][co].x += v.x*w.x - v.y*w.y;
                        acc[s][co].y += v.x*w.y + v.y*w.x;
                    }
            }
        }
    }

#pragma unroll
    for (int s = 0; s < NS; ++s) {
        int p = tid + s*256;
        if (p >= TOT) continue;
        int r = p / ROUT, c = p - r*ROUT;
        int gi = oi + r, gj = oj + c;
        bool inb = (gi >= 0) & (gi < NP) & (gj >= 0) & (gj < NP);
        if (THETA) {
            int thidx = inb ? (b*NSQ + gi*NP + gj) : 0;
            float tr = thr[thidx], tim = thi[thidx];
#pragma unroll
            for (int co = 0; co < COUT; ++co) {
                float2 a = acc[s][co];
                acc[s][co] = make_float2(a.x*tr - a.y*tim, a.x*tim + a.y*tr);
            }
        }
#pragma unroll
        for (int co = 0; co < COUT; ++co) {
            float2 val = inb ? acc[s][co] : make_float2(0.f, 0.f);
            if (STORE_GLOBAL) {
                gout[((b*4) << 16) + ((gi + 128) & 255)*NP + ((gj + 128) & 255)] = val;
            } else {
                dst[co*TOT + p] = val;
            }
        }
    }
}

// ---------------- fused conv stack kernel: CB ch0 -> CA ch0 ----------------
// 16x16 output tiles in SHIFTED coordinate space; fftshift folded into S0 load,
// ifftshift into final store, theta into stage 3.
__global__ __launch_bounds__(256) void fusedconv_kernel(const float* __restrict__ thr,
                                                        const float* __restrict__ thi, int it)
{
    if (it >= g_K) return;
    __shared__ float2 aX[2304];   // S0 (784), S2 (4*576), S4 (4*400)
    __shared__ float2 aY[2704];   // S1 (4*676), S3 (484), S5 (4*324)
    __shared__ float2 s_w[432];   // W1|W2|W3|W3T|W2T|W1T

    const int tid = threadIdx.x;
    const int blk = blockIdx.x;
    const int b  = blk >> 8;
    const int ti = (blk >> 4) & 15, tj = blk & 15;
    const int base = (b*4) << 16;

    for (int k = tid; k < 432; k += 256) {
        float2 v;
        if      (k < 36)  v = g_W1 [b*36  + k];
        else if (k < 180) v = g_W2 [b*144 + (k-36)];
        else if (k < 216) v = g_W3 [b*36  + (k-180)];
        else if (k < 252) v = g_W3T[b*36  + (k-216)];
        else if (k < 396) v = g_W2T[b*144 + (k-252)];
        else              v = g_W1T[b*36  + (k-396)];
        s_w[k] = v;
    }

    const int oi0 = ti*16 - 6, oj0 = tj*16 - 6;
    for (int p = tid; p < 784; p += 256) {
        int r = p / 28, c = p - r*28;
        int gi = oi0 + r, gj = oj0 + c;
        float2 v = make_float2(0.f, 0.f);
        if (gi >= 0 && gi < NP && gj >= 0 && gj < NP)
            v = g_CB[base + ((gi + 128) & 255)*NP + ((gj + 128) & 255)];
        aX[p] = v;
    }
    __syncthreads();
    stage_conv<1,4,28,false,false>(aX, aY, s_w,       oi0+1, oj0+1, b, thr, thi, tid, nullptr);
    __syncthreads();
    stage_conv<4,4,26,false,false>(aY, aX, s_w + 36,  oi0+2, oj0+2, b, thr, thi, tid, nullptr);
    __syncthreads();
    stage_conv<4,1,24,true ,false>(aX, aY, s_w + 180, oi0+3, oj0+3, b, thr, thi, tid, nullptr);
    __syncthreads();
    stage_conv<1,4,22,false,false>(aY, aX, s_w + 216, oi0+4, oj0+4, b, thr, thi, tid, nullptr);
    __syncthreads();
    stage_conv<4,4,20,false,false>(aX, aY, s_w + 252, oi0+5, oj0+5, b, thr, thi, tid, nullptr);
    __syncthreads();
    stage_conv<4,1,18,false,true >(aY, aX, s_w + 396, oi0+6, oj0+6, b, thr, thi, tid, g_CA);
}

// ---------------- fused: x_new = x + e ; r = f - A(x+e) ; e = CA ch0 ----------------
__global__ void xupd_resid_kernel(const float* __restrict__ f, const float* __restrict__ kA, int it)
{
    if (it >= g_K) return;
    int tid = blockIdx.x*blockDim.x + threadIdx.x;
    if (tid >= Bn*RSZ) return;
    int b = tid / RSZ, rem = tid - b*RSZ;
    int i = rem / Nn, j = rem - i*Nn;
    const float2* e = g_CA + ((b*4) << 16);
    float acc = 0.f;
#pragma unroll
    for (int a = 0; a < 3; ++a) {
        int si = i + a - 1;
        if (si < 0 || si >= Nn) continue;
#pragma unroll
        for (int b2 = 0; b2 < 3; ++b2) {
            int sj = j + b2 - 1;
            if (sj < 0 || sj >= Nn) continue;
            float xv = g_x[b*RSZ + si*Nn + sj] + e[si*NP + sj].x;
            acc += xv * kA[b*9 + a*3 + b2];
        }
    }
    g_xB[tid] = g_x[tid] + e[i*NP + j].x;
    g_r[tid]  = f[tid] - acc;
}

// ---------------- norm: 256-block partial + finalize ----------------
__global__ __launch_bounds__(256) void norm_partial_kernel(const float* __restrict__ f)
{
    __shared__ float sr[256], sf[256];
    int tid = threadIdx.x;
    float ar = 0.f, af = 0.f;
    for (int i = blockIdx.x*256 + tid; i < Bn*RSZ; i += 256*256) {
        float rv = g_r[i]; ar += rv*rv;
        float fv = f[i];   af += fv*fv;
    }
    sr[tid] = ar; sf[tid] = af;
    __syncthreads();
    for (int s = 128; s > 0; s >>= 1) {
        if (tid < s) { sr[tid] += sr[tid+s]; sf[tid] += sf[tid+s]; }
        __syncthreads();
    }
    if (tid == 0) {
        atomicAdd(&g_acc[0], sr[0]);
        atomicAdd(&g_acc[1], sf[0]);
    }
}

__global__ void norm_fin_kernel(float* __restrict__ out)
{
    out[0] = sqrtf(g_acc[0] / g_acc[1]);
}

// ---------------- driver ----------------
extern "C" void kernel_launch(void* const* d_in, const int* in_sizes, int n_in,
                              void* d_out, int out_size, void* d_ws, size_t ws_size,
                              hipStream_t stream)
{
    const float* f   = (const float*)d_in[0];
    const float* kA  = (const float*)d_in[1];
    const float* w1r = (const float*)d_in[2];
    const float* w1i = (const float*)d_in[3];
    const float* w2r = (const float*)d_in[4];
    const float* w2i = (const float*)d_in[5];
    const float* w3r = (const float*)d_in[6];
    const float* w3i = (const float*)d_in[7];
    const float* thr = (const float*)d_in[8];
    const float* thi = (const float*)d_in[9];
    const int* epoch = (const int*)d_in[10];
    float* out = (float*)d_out;

    init_kernel<<<1, 256, 0, stream>>>(w1r, w1i, w2r, w2i, w3r, w3i, epoch);

    const int nP = (Bn*RSZ + 255) / 256;
    const float inv256 = 1.f / 256.f;

    for (int it = 0; it < 10; it++) {
        jacobi_kernel<<<dim3(4,4,16), 512, 0, stream>>>(f, kA, it);
        fft_kernel<1, false, true ><<<512, 256, 0, stream>>>(1, inv256, it);  // expand rows -> CA
        fft_kernel<1, true,  false><<<512, 256, 0, stream>>>(0, inv256, it);  // cols CA -> CB
        fusedconv_kernel<<<4096, 256, 0, stream>>>(thr, thi, it);             // CB -> CA (6 convs + theta)
        fft_kernel<-1, false, false><<<512, 256, 0, stream>>>(0, 1.f, it);    // fwd rows CA -> CB
        fft_kernel<-1, true,  false><<<512, 256, 0, stream>>>(1, 1.f, it);    // fwd cols CB -> CA
        xupd_resid_kernel<<<nP, 256, 0, stream>>>(f, kA, it);
    }
    norm_partial_kernel<<<256, 256, 0, stream>>>(f);
    norm_fin_kernel<<<1, 1, 0, stream>>>(out);
}